// Round 1
// baseline (1933.917 us; speedup 1.0000x reference)
//
#include <hip/hip_runtime.h>
#include <cstdint>
#include <cstddef>

// SAMGuidedCrossAttention: B=4, C=256, H=W=256, heads=8, ws=8, d=32
// FULLY FUSED design:
//   prep_weights: wq/wk/wv/wp f32 -> bf16 in d_ws (512 KB, only workspace use)
//   fused_win_attn: one block = 4 horizontally-adjacent windows (one batch),
//     processed sequentially so every 128B HBM line of x / out is fully
//     consumed inside one block. Per window:
//       stage Xkv+Xq [64 pos][256 c] bf16 (stride 264 -> b128 B-frags)
//       KV GEMM (waves 0-3 = K, 4-7 = V; xkv staged ONCE for both)
//       Q GEMM  (wave = head)
//       windowed attention (swizzled K/Q/V in LDS, proven softmax/P path)
//       fused output conv (wp) -> f32 out
//     Cross-window pipelining: next window's x float4 loads issued during
//     the attention phase.
// Eliminates the 800 MB QKV workspace round trip and 7 of 9 launches.
// HBM floor: 512 MB read + 256 MB write = 768 MB.

typedef __attribute__((ext_vector_type(8))) short bfx8;   // 8 bf16 (4 VGPR)
typedef __attribute__((ext_vector_type(4))) float f32x4;  // MFMA acc / float4

#define HW 65536
#define NC 256

// LDS regions (ushort indices). Total 66560 ushorts = 130 KB.
#define XKV_BASE 0        // [64 pos][264] staged xkv ; later y_t [64][256] swz
#define XQ_BASE  16896    // [64 pos][264] staged xq  ; later Q [8][64][32] swz
#define KB_BASE  33792    // K [8 head][64 pos][32 d] swz ^((pos&3)<<4) ; later P per wave
#define VB_BASE  50176    // V [8 head][32 d][64 pos] swz ^((d&7)<<4)
#define LDS_TOTAL 66560

__device__ __forceinline__ unsigned short f2bf(float f) {
  union { float f; unsigned u; } v; v.f = f;
  unsigned r = v.u + 0x7FFFu + ((v.u >> 16) & 1u);  // RNE
  return (unsigned short)(r >> 16);
}

__global__ __launch_bounds__(256) void prep_weights(
    const float* __restrict__ wq, const float* __restrict__ wk,
    const float* __restrict__ wv, const float* __restrict__ wp,
    unsigned short* __restrict__ dst) {
  int i = blockIdx.x * 256 + threadIdx.x;  // grid 256 x 256
  dst[i]          = f2bf(wq[i]);
  dst[i + 65536]  = f2bf(wk[i]);
  dst[i + 131072] = f2bf(wv[i]);
  dst[i + 196608] = f2bf(wp[i]);
}

__global__ __launch_bounds__(512, 2) void fused_win_attn(
    const float* __restrict__ xq_g, const float* __restrict__ xkv_g,
    const unsigned short* __restrict__ wbf,
    const float* __restrict__ bq_p, const float* __restrict__ bk_p,
    const float* __restrict__ bv_p, const float* __restrict__ bp_p,
    float* __restrict__ out) {
  __shared__ __align__(16) unsigned short lds[LDS_TOTAL];

  const int tid = threadIdx.x;
  const int lane = tid & 63;
  const int wid = tid >> 6;        // 0..7
  const int g = lane >> 4;         // k-group
  const int qh = lane & 15;
  const int batch = blockIdx.y;
  const int wb = blockIdx.x;       // 0..255
  const int wr = wb >> 3;          // window row 0..31
  const int wc0 = (wb & 7) << 2;   // first of 4 consecutive window cols
  const int h0 = wr * 8;

  const float* xq_b = xq_g + (size_t)batch * NC * HW;
  const float* xkv_b = xkv_g + (size_t)batch * NC * HW;
  float* out_b = out + (size_t)batch * NC * HW;

  // staging thread mapping: thread -> channel pair (2cp, 2cp+1), row group rh
  const int cp = tid & 127;
  const int rh = tid >> 7;         // 0..3
  const size_t cofs0 = (size_t)(2 * cp) * HW;
  const size_t cofs1 = cofs0 + HW;

  const float scale = 0.17677669529663687f;  // 1/sqrt(32)

  f32x4 skv[8], sq[8];  // in-flight x tiles (pipelined across windows)

  auto issue_loads = [&](int wi_) {
    const int w0_ = (wc0 + wi_) * 8;
#pragma unroll
    for (int k = 0; k < 4; ++k) {
      int r_ = rh * 2 + (k >> 1);
      int off_ = (h0 + r_) * 256 + w0_ + (k & 1) * 4;
      skv[k * 2]     = *(const f32x4*)(xkv_b + cofs0 + off_);
      skv[k * 2 + 1] = *(const f32x4*)(xkv_b + cofs1 + off_);
      sq[k * 2]      = *(const f32x4*)(xq_b + cofs0 + off_);
      sq[k * 2 + 1]  = *(const f32x4*)(xq_b + cofs1 + off_);
    }
  };

  issue_loads(0);

  for (int wi = 0; wi < 4; ++wi) {
    if (wi) __syncthreads();  // prior window's LDS reads complete

    // ---- stage X tiles to LDS as bf16, layout [pos][c] stride 264 ----
#pragma unroll
    for (int k = 0; k < 4; ++k) {
      int r = rh * 2 + (k >> 1);
      int pb = r * 8 + (k & 1) * 4;
      f32x4 a0 = skv[k * 2], a1 = skv[k * 2 + 1];
      f32x4 b0 = sq[k * 2], b1 = sq[k * 2 + 1];
#pragma unroll
      for (int e = 0; e < 4; ++e) {
        int p = pb + e;
        *(unsigned*)&lds[XKV_BASE + p * 264 + 2 * cp] =
            (unsigned)f2bf(a0[e]) | ((unsigned)f2bf(a1[e]) << 16);
        *(unsigned*)&lds[XQ_BASE + p * 264 + 2 * cp] =
            (unsigned)f2bf(b0[e]) | ((unsigned)f2bf(b1[e]) << 16);
      }
    }
    __syncthreads();  // staged tiles visible

    // ---- KV GEMM: waves 0-3 compute K, waves 4-7 compute V ----
    {
      const int mode = wid >> 2;  // 0=K, 1=V
      const int sub = wid & 3;
      const unsigned short* wkv = wbf + 65536 + mode * 65536;
      f32x4 acc[4][4];
#pragma unroll
      for (int i = 0; i < 4; ++i)
#pragma unroll
        for (int j = 0; j < 4; ++j) acc[i][j] = (f32x4){0.f, 0.f, 0.f, 0.f};

      bfx8 afr[4];
#pragma unroll
      for (int mt = 0; mt < 4; ++mt)
        afr[mt] = *(const bfx8*)(wkv + (sub * 64 + mt * 16 + qh) * 256 + g * 8);

      for (int ks = 0; ks < 8; ++ks) {
        bfx8 nafr[4];
        if (ks < 7) {
#pragma unroll
          for (int mt = 0; mt < 4; ++mt)
            nafr[mt] = *(const bfx8*)(wkv + (sub * 64 + mt * 16 + qh) * 256 + (ks + 1) * 32 + g * 8);
        }
#pragma unroll
        for (int nt = 0; nt < 4; ++nt) {
          bfx8 bfr = *(const bfx8*)&lds[XKV_BASE + (nt * 16 + qh) * 264 + ks * 32 + g * 8];
#pragma unroll
          for (int mt = 0; mt < 4; ++mt)
            acc[mt][nt] = __builtin_amdgcn_mfma_f32_16x16x32_bf16(afr[mt], bfr, acc[mt][nt], 0, 0, 0);
        }
        if (ks < 7) {
#pragma unroll
          for (int mt = 0; mt < 4; ++mt) afr[mt] = nafr[mt];
        }
      }

      // K/V accs -> LDS (+bias, bf16)
      const float* bias = (mode == 0) ? bk_p : bv_p;
#pragma unroll
      for (int mt = 0; mt < 4; ++mt) {
        int obase = sub * 64 + mt * 16 + g * 4;
        f32x4 bb = *(const f32x4*)&bias[obase];
        int head = obase >> 5;
        int dbase = obase & 31;
#pragma unroll
        for (int nt = 0; nt < 4; ++nt) {
          int pos = nt * 16 + qh;
          f32x4 a = acc[mt][nt];
          if (mode == 0) {
            uint2 pv;
            pv.x = (unsigned)f2bf(a.x + bb[0]) | ((unsigned)f2bf(a.y + bb[1]) << 16);
            pv.y = (unsigned)f2bf(a.z + bb[2]) | ((unsigned)f2bf(a.w + bb[3]) << 16);
            unsigned byte = ((unsigned)(head * 4096 + pos * 64 + dbase * 2)) ^ (((unsigned)(pos & 3)) << 4);
            *(uint2*)((char*)&lds[KB_BASE] + byte) = pv;
          } else {
            float vj[4] = {a.x + bb[0], a.y + bb[1], a.z + bb[2], a.w + bb[3]};
#pragma unroll
            for (int j = 0; j < 4; ++j) {
              int d = dbase + j;
              unsigned byte = ((unsigned)(head * 4096 + d * 128 + pos * 2)) ^ (((unsigned)(d & 7)) << 4);
              *(unsigned short*)((char*)&lds[VB_BASE] + byte) = f2bf(vj[j]);
            }
          }
        }
      }
    }

    // ---- Q GEMM: wave = head, 32 out channels ----
    {
      f32x4 qacc[2][4];
#pragma unroll
      for (int i = 0; i < 2; ++i)
#pragma unroll
        for (int j = 0; j < 4; ++j) qacc[i][j] = (f32x4){0.f, 0.f, 0.f, 0.f};

      bfx8 afr[2];
#pragma unroll
      for (int mt = 0; mt < 2; ++mt)
        afr[mt] = *(const bfx8*)(wbf + (wid * 32 + mt * 16 + qh) * 256 + g * 8);

      for (int ks = 0; ks < 8; ++ks) {
        bfx8 nafr[2];
        if (ks < 7) {
#pragma unroll
          for (int mt = 0; mt < 2; ++mt)
            nafr[mt] = *(const bfx8*)(wbf + (wid * 32 + mt * 16 + qh) * 256 + (ks + 1) * 32 + g * 8);
        }
#pragma unroll
        for (int nt = 0; nt < 4; ++nt) {
          bfx8 bfr = *(const bfx8*)&lds[XQ_BASE + (nt * 16 + qh) * 264 + ks * 32 + g * 8];
#pragma unroll
          for (int mt = 0; mt < 2; ++mt)
            qacc[mt][nt] = __builtin_amdgcn_mfma_f32_16x16x32_bf16(afr[mt], bfr, qacc[mt][nt], 0, 0, 0);
        }
        if (ks < 7) { afr[0] = nafr[0]; afr[1] = nafr[1]; }
      }

      __syncthreads();  // all Xq reads done -> safe to alias Q over XQ region

#pragma unroll
      for (int mt = 0; mt < 2; ++mt) {
        int obase = wid * 32 + mt * 16 + g * 4;
        f32x4 bb = *(const f32x4*)&bq_p[obase];
        int dbase = mt * 16 + g * 4;
#pragma unroll
        for (int nt = 0; nt < 4; ++nt) {
          int pos = nt * 16 + qh;
          f32x4 a = qacc[mt][nt];
          uint2 pv;
          pv.x = (unsigned)f2bf(a.x + bb[0]) | ((unsigned)f2bf(a.y + bb[1]) << 16);
          pv.y = (unsigned)f2bf(a.z + bb[2]) | ((unsigned)f2bf(a.w + bb[3]) << 16);
          unsigned byte = ((unsigned)(wid * 4096 + pos * 64 + dbase * 2)) ^ (((unsigned)(pos & 3)) << 4);
          *(uint2*)((char*)&lds[XQ_BASE] + byte) = pv;
        }
      }
    }
    __syncthreads();  // K/V/Q all visible

    // ---- windowed attention: wave = head wid ----
    {
      char* kbase = (char*)&lds[KB_BASE] + wid * 4096;
      char* qbase = (char*)&lds[XQ_BASE] + wid * 4096;
      char* vbase = (char*)&lds[VB_BASE] + wid * 4096;

      bfx8 kf[4], qf[4];
#pragma unroll
      for (int t = 0; t < 4; ++t) {
        int pos = t * 16 + qh;
        unsigned off = ((unsigned)(pos * 64 + g * 16)) ^ (((unsigned)(pos & 3)) << 4);
        kf[t] = *(const bfx8*)(kbase + off);
        qf[t] = *(const bfx8*)(qbase + off);
      }

      // S^T[kpos][q] = sum_d K[kpos][d]*Q[q][d]
      f32x4 zero = {0.f, 0.f, 0.f, 0.f};
      f32x4 st[4][4];
#pragma unroll
      for (int kt = 0; kt < 4; ++kt)
#pragma unroll
        for (int qt = 0; qt < 4; ++qt)
          st[kt][qt] = __builtin_amdgcn_mfma_f32_16x16x32_bf16(kf[kt], qf[qt], zero, 0, 0, 0);

      // softmax over kpos: in-lane 16 vals + shfl across g groups
      float rv[4];
#pragma unroll
      for (int qt = 0; qt < 4; ++qt) {
        float m = -1e30f;
#pragma unroll
        for (int kt = 0; kt < 4; ++kt) {
          f32x4 v = st[kt][qt];
          m = fmaxf(m, fmaxf(fmaxf(v.x, v.y), fmaxf(v.z, v.w)));
        }
        m = fmaxf(m, __shfl_xor(m, 16, 64));
        m = fmaxf(m, __shfl_xor(m, 32, 64));
        float ssum = 0.f;
#pragma unroll
        for (int kt = 0; kt < 4; ++kt) {
          f32x4 v = st[kt][qt], e;
          e.x = __expf((v.x - m) * scale);
          e.y = __expf((v.y - m) * scale);
          e.z = __expf((v.z - m) * scale);
          e.w = __expf((v.w - m) * scale);
          ssum += e.x + e.y + e.z + e.w;
          st[kt][qt] = e;
        }
        ssum += __shfl_xor(ssum, 16, 64);
        ssum += __shfl_xor(ssum, 32, 64);
        rv[qt] = 1.f / ssum;
      }

      // PV via per-wave P tile (reuses own head's K region)
      f32x4 ot[2][4];
#pragma unroll
      for (int dt = 0; dt < 2; ++dt)
#pragma unroll
        for (int qt = 0; qt < 4; ++qt) ot[dt][qt] = zero;

#pragma unroll
      for (int s = 0; s < 2; ++s) {
#pragma unroll
        for (int qt = 0; qt < 4; ++qt) {
          int q = qt * 16 + qh;
          unsigned sw = ((unsigned)(q & 3)) << 4;
          float r = rv[qt];
#pragma unroll
          for (int k2 = 0; k2 < 2; ++k2) {
            f32x4 e = st[s * 2 + k2][qt];
            uint2 pv;
            pv.x = (unsigned)f2bf(e.x * r) | ((unsigned)f2bf(e.y * r) << 16);
            pv.y = (unsigned)f2bf(e.z * r) | ((unsigned)f2bf(e.w * r) << 16);
            unsigned byte = ((unsigned)(q * 64 + k2 * 32 + g * 8)) ^ sw;
            *(uint2*)(kbase + byte) = pv;
          }
        }
        bfx8 pf[4];
#pragma unroll
        for (int qt = 0; qt < 4; ++qt) {
          int q = qt * 16 + qh;
          unsigned byte = ((unsigned)(q * 64 + g * 16)) ^ (((unsigned)(q & 3)) << 4);
          pf[qt] = *(const bfx8*)(kbase + byte);
        }
#pragma unroll
        for (int dt = 0; dt < 2; ++dt) {
          int drow = dt * 16 + qh;
          unsigned voff = ((unsigned)(drow * 128 + (s * 32 + g * 8) * 2)) ^ (((unsigned)(drow & 7)) << 4);
          bfx8 vf = *(const bfx8*)(vbase + voff);
#pragma unroll
          for (int qt = 0; qt < 4; ++qt)
            ot[dt][qt] = __builtin_amdgcn_mfma_f32_16x16x32_bf16(vf, pf[qt], ot[dt][qt], 0, 0, 0);
        }
      }

      // attention out -> y_t[pos][c] (swizzled, aliases XKV region)
#pragma unroll
      for (int dt = 0; dt < 2; ++dt) {
        int cb = wid * 32 + dt * 16 + g * 4;
#pragma unroll
        for (int qt = 0; qt < 4; ++qt) {
          int pos = qt * 16 + qh;
          f32x4 a = ot[dt][qt];
          uint2 pv;
          pv.x = (unsigned)f2bf(a.x) | ((unsigned)f2bf(a.y) << 16);
          pv.y = (unsigned)f2bf(a.z) | ((unsigned)f2bf(a.w) << 16);
          unsigned byte = ((unsigned)(pos * 512 + cb * 2)) ^ (((unsigned)(pos & 7)) << 4);
          *(uint2*)((char*)lds + byte) = pv;
        }
      }
    }

    // issue next window's x loads: latency hides under conv phase
    if (wi < 3) issue_loads(wi + 1);

    __syncthreads();  // y_t complete

    // ---- output conv: wave wid -> out channels [32*wid, +32) ----
    {
      const unsigned short* wp_ = wbf + 196608;
      f32x4 cacc[2][4];
#pragma unroll
      for (int i = 0; i < 2; ++i)
#pragma unroll
        for (int j = 0; j < 4; ++j) cacc[i][j] = (f32x4){0.f, 0.f, 0.f, 0.f};

      bfx8 af[2];
#pragma unroll
      for (int mt = 0; mt < 2; ++mt)
        af[mt] = *(const bfx8*)(wp_ + (wid * 32 + mt * 16 + qh) * 256 + g * 8);

      for (int ks = 0; ks < 8; ++ks) {
        bfx8 naf[2];
        if (ks < 7) {
#pragma unroll
          for (int mt = 0; mt < 2; ++mt)
            naf[mt] = *(const bfx8*)(wp_ + (wid * 32 + mt * 16 + qh) * 256 + (ks + 1) * 32 + g * 8);
        }
#pragma unroll
        for (int nt = 0; nt < 4; ++nt) {
          int pos = nt * 16 + qh;
          unsigned byte = ((unsigned)(pos * 512 + ks * 64 + g * 16)) ^ (((unsigned)(pos & 7)) << 4);
          bfx8 bfr = *(const bfx8*)((char*)lds + byte);
#pragma unroll
          for (int mt = 0; mt < 2; ++mt)
            cacc[mt][nt] = __builtin_amdgcn_mfma_f32_16x16x32_bf16(af[mt], bfr, cacc[mt][nt], 0, 0, 0);
        }
        if (ks < 7) { af[0] = naf[0]; af[1] = naf[1]; }
      }

      const int w0 = (wc0 + wi) * 8;
#pragma unroll
      for (int mt = 0; mt < 2; ++mt) {
        int o0 = wid * 32 + mt * 16 + g * 4;
        f32x4 bb = *(const f32x4*)&bp_p[o0];
#pragma unroll
        for (int nt = 0; nt < 4; ++nt) {
          int pos = nt * 16 + qh;
          float* pp = out_b + (size_t)o0 * HW + (h0 + (pos >> 3)) * 256 + w0 + (pos & 7);
          pp[0]      = cacc[mt][nt].x + bb[0];
          pp[HW]     = cacc[mt][nt].y + bb[1];
          pp[2 * HW] = cacc[mt][nt].z + bb[2];
          pp[3 * HW] = cacc[mt][nt].w + bb[3];
        }
      }
    }
  }  // window loop
}

extern "C" void kernel_launch(void* const* d_in, const int* in_sizes, int n_in,
                              void* d_out, int out_size, void* d_ws, size_t ws_size,
                              hipStream_t stream) {
  const float* q_feat = (const float*)d_in[0];
  const float* kv_feat = (const float*)d_in[1];
  const float* wq = (const float*)d_in[2];
  const float* bq = (const float*)d_in[3];
  const float* wk = (const float*)d_in[4];
  const float* bk = (const float*)d_in[5];
  const float* wv = (const float*)d_in[6];
  const float* bv = (const float*)d_in[7];
  const float* wp = (const float*)d_in[8];
  const float* bp = (const float*)d_in[9];
  float* out = (float*)d_out;

  unsigned short* wbf = (unsigned short*)d_ws;  // 4 x 65536 bf16 = 512 KB

  hipLaunchKernelGGL(prep_weights, dim3(256), dim3(256), 0, stream, wq, wk, wv, wp, wbf);
  hipLaunchKernelGGL(fused_win_attn, dim3(256, 4), dim3(512), 0, stream,
                     q_feat, kv_feat, wbf, bq, bk, bv, bp, out);
}

// Round 2
// 632.204 us; speedup vs baseline: 3.0590x; 3.0590x over previous
//
#include <hip/hip_runtime.h>
#include <cstdint>
#include <cstddef>

// SAMGuidedCrossAttention: B=4, C=256, H=W=256, heads=8, ws=8, d=32
// Structure (lesson from fused-kernel failure: keep lane->contiguous-position
// loads; the QKV HBM round trip is cheap, gather-style x reads are not):
//   prep_weights: wq/wk/wv/wp f32 -> bf16
//   qkv_gemm: grid(2048,1,NB), 256 thr. bid&1==0: Q. bid&1==1: K AND V fused
//     (xkv staged ONCE -> halves xkv HBM reads). Full-K single-stage (32 KB,
//     conflict-free swizzled b128 writes/reads), ONE barrier before MFMA loop
//     (was 16). Q/K epilogue: direct packed uint2 stores. V: LDS transpose.
//   attn_conv: proven 704us kernel + XCD-chunked winl swizzle so the 4
//     windows sharing each 128B output line stay in one XCD's L2.
// Batched path (ws permitting): 1 qkv launch + 1 attn launch for all batches.

typedef __attribute__((ext_vector_type(8))) short bfx8;   // 8 bf16 (4 VGPR)
typedef __attribute__((ext_vector_type(4))) float f32x4;  // MFMA acc

#define HW 65536
#define NC 256
#define QKV_STRIDE 16777216UL  // ushorts per tensor per batch (1024*8*64*32)

__device__ __forceinline__ unsigned short f2bf(float f) {
  union { float f; unsigned u; } v; v.f = f;
  unsigned r = v.u + 0x7FFFu + ((v.u >> 16) & 1u);  // RNE
  return (unsigned short)(r >> 16);
}

__global__ __launch_bounds__(256) void prep_weights(
    const float* __restrict__ wq, const float* __restrict__ wk,
    const float* __restrict__ wv, const float* __restrict__ wp,
    unsigned short* __restrict__ dst) {
  int i = blockIdx.x * 256 + threadIdx.x;  // grid 256 x 256
  dst[i]          = f2bf(wq[i]);
  dst[i + 65536]  = f2bf(wk[i]);
  dst[i + 131072] = f2bf(wv[i]);
  dst[i + 196608] = f2bf(wp[i]);
}

// One GEMM pass: acc[mt][nt] = W[256x256] * Xs over staged tile.
// Xs layout: [n 64][c 256] bf16, row stride 512 B, byte ^ ((n&7)<<4).
__device__ __forceinline__ void gemm_pass(
    const unsigned short* __restrict__ wmat, const unsigned char* __restrict__ smem,
    int wid, int g, int qh, f32x4 (&acc)[4][4]) {
#pragma unroll
  for (int i = 0; i < 4; ++i)
#pragma unroll
    for (int j = 0; j < 4; ++j) acc[i][j] = (f32x4){0.f, 0.f, 0.f, 0.f};

  bfx8 afr[4];
#pragma unroll
  for (int mt = 0; mt < 4; ++mt)
    afr[mt] = *(const bfx8*)(wmat + (wid * 64 + mt * 16 + qh) * 256 + g * 8);

  for (int ks = 0; ks < 8; ++ks) {
    bfx8 naf[4];
    if (ks < 7) {
#pragma unroll
      for (int mt = 0; mt < 4; ++mt)
        naf[mt] = *(const bfx8*)(wmat + (wid * 64 + mt * 16 + qh) * 256 + (ks + 1) * 32 + g * 8);
    }
#pragma unroll
    for (int nt = 0; nt < 4; ++nt) {
      unsigned byte = ((unsigned)((nt * 16 + qh) * 512 + ks * 64 + g * 16)) ^
                      (((unsigned)(qh & 7)) << 4);
      bfx8 bfr = *(const bfx8*)(smem + byte);
#pragma unroll
      for (int mt = 0; mt < 4; ++mt)
        acc[mt][nt] = __builtin_amdgcn_mfma_f32_16x16x32_bf16(afr[mt], bfr, acc[mt][nt], 0, 0, 0);
    }
    if (ks < 7) {
#pragma unroll
      for (int mt = 0; mt < 4; ++mt) afr[mt] = naf[mt];
    }
  }
}

// Direct windowed store for Q/K layout [win*8+head][pos 64][d 32] (+bias).
__device__ __forceinline__ void store_qk(
    const f32x4 (&acc)[4][4], const float* __restrict__ bias,
    unsigned short* __restrict__ outw, int n0, int wid, int g, int qh) {
  const int h_img = n0 >> 8, w0b = n0 & 255;
#pragma unroll
  for (int mt = 0; mt < 4; ++mt) {
    int o = wid * 64 + mt * 16 + g * 4;
    f32x4 bb = *(const f32x4*)&bias[o];
    int head = o >> 5, dbase = o & 31;
#pragma unroll
    for (int nt = 0; nt < 4; ++nt) {
      int n = nt * 16 + qh;
      int w_img = w0b + n;
      int win = ((h_img >> 3) << 5) + (w_img >> 3);
      int pos = ((h_img & 7) << 3) + (w_img & 7);
      f32x4 a = acc[mt][nt];
      uint2 pv;
      pv.x = (unsigned)f2bf(a.x + bb.x) | ((unsigned)f2bf(a.y + bb.y) << 16);
      pv.y = (unsigned)f2bf(a.z + bb.z) | ((unsigned)f2bf(a.w + bb.w) << 16);
      *(uint2*)&outw[((size_t)(win * 8 + head) * 64 + pos) * 32 + dbase] = pv;
    }
  }
}

// ---------------- QKV projection GEMM ----------------
// grid (2048, 1, NB), 256 thr (4 waves). bid&1: 0 = Q, 1 = K+V (shared stage).
__global__ __launch_bounds__(256) void qkv_gemm(
    const float* __restrict__ xq, const float* __restrict__ xkv,
    const unsigned short* __restrict__ wbf,
    const float* __restrict__ bq, const float* __restrict__ bk,
    const float* __restrict__ bv,
    unsigned short* __restrict__ q_w, unsigned short* __restrict__ k_w,
    unsigned short* __restrict__ v_w, int batch0, int batched) {
  __shared__ __align__(16) unsigned char smem[36864];  // stage 32KB | V-epi 36KB

  const int tid = threadIdx.x;
  const int lane = tid & 63;
  const int wid = tid >> 6;
  const int g = lane >> 4;
  const int qh = lane & 15;
  const int mode = blockIdx.x & 1;
  const int n0 = (int)(blockIdx.x >> 1) * 64;
  const int batch = batch0 + blockIdx.z;
  const size_t qofs = batched ? (size_t)blockIdx.z * QKV_STRIDE : 0;
  const float* x = (mode ? xkv : xq) + (size_t)batch * NC * HW;

  // ---- stage X[256 c][n0..n0+64) -> Xs[n][c] bf16 (full K, one shot) ----
  {
    const int sn = tid & 63;   // lane -> contiguous n (coalesced 256B/row)
    const int oc = tid >> 6;
#pragma unroll
    for (int it = 0; it < 8; ++it) {
      int c8 = (it * 4 + oc) * 8;
      const float* xp = x + (size_t)c8 * HW + n0 + sn;
      float v0 = xp[0],      v1 = xp[HW],     v2 = xp[2 * HW], v3 = xp[3 * HW];
      float v4 = xp[4 * HW], v5 = xp[5 * HW], v6 = xp[6 * HW], v7 = xp[7 * HW];
      uint4 u;
      u.x = (unsigned)f2bf(v0) | ((unsigned)f2bf(v1) << 16);
      u.y = (unsigned)f2bf(v2) | ((unsigned)f2bf(v3) << 16);
      u.z = (unsigned)f2bf(v4) | ((unsigned)f2bf(v5) << 16);
      u.w = (unsigned)f2bf(v6) | ((unsigned)f2bf(v7) << 16);
      unsigned byte = ((unsigned)(sn * 512 + c8 * 2)) ^ (((unsigned)(sn & 7)) << 4);
      *(uint4*)(smem + byte) = u;  // 16B write, conflict-free
    }
  }
  __syncthreads();  // the ONLY barrier before the MFMA stream

  f32x4 acc[4][4];
  if (mode == 0) {
    gemm_pass(wbf, smem, wid, g, qh, acc);                 // wq
    store_qk(acc, bq, q_w + qofs, n0, wid, g, qh);
  } else {
    gemm_pass(wbf + 65536, smem, wid, g, qh, acc);         // wk
    store_qk(acc, bk, k_w + qofs, n0, wid, g, qh);
    gemm_pass(wbf + 131072, smem, wid, g, qh, acc);        // wv (stage reused)
    __syncthreads();  // all stage reads done -> alias V-epi over stage
    unsigned short* Vt = (unsigned short*)smem;            // [o 256][n 64 pad 72]
#pragma unroll
    for (int mt = 0; mt < 4; ++mt) {
      int o = wid * 64 + mt * 16 + g * 4;
      f32x4 bb = *(const f32x4*)&bv[o];
#pragma unroll
      for (int nt = 0; nt < 4; ++nt) {
        int n = nt * 16 + qh;
        f32x4 a = acc[mt][nt];
        Vt[(o + 0) * 72 + n] = f2bf(a.x + bb.x);
        Vt[(o + 1) * 72 + n] = f2bf(a.y + bb.y);
        Vt[(o + 2) * 72 + n] = f2bf(a.z + bb.z);
        Vt[(o + 3) * 72 + n] = f2bf(a.w + bb.w);
      }
    }
    __syncthreads();
    const int h_img = n0 >> 8, w0b = n0 & 255;
    unsigned short* vw = v_w + qofs;
#pragma unroll
    for (int it = 0; it < 8; ++it) {
      int id = it * 256 + tid;
      int o = id >> 3, oct = id & 7;
      uint4 val = *(const uint4*)&Vt[o * 72 + oct * 8];
      int head = o >> 5, dd = o & 31;
      int win = ((h_img >> 3) << 5) + (w0b >> 3) + oct;
      *(uint4*)&vw[((size_t)(win * 8 + head) * 32 + dd) * 64 + ((h_img & 7) << 3)] = val;
    }
  }
}

// ---------------- fused windowed attention + output conv ----------------
// Block: 256 thr (4 waves) = 1 window. Wave handles heads {wid, wid+4}.
__global__ __launch_bounds__(256) void attn_conv(
    const unsigned short* __restrict__ q_w, const unsigned short* __restrict__ k_w,
    const unsigned short* __restrict__ v_w, const unsigned short* __restrict__ wpbf,
    const float* __restrict__ bp, float* __restrict__ out, int batch0, int batched) {
  __shared__ unsigned short P_lds[4][2048];  // per-wave P half-tile [64 q][32 k], swizzled
  __shared__ unsigned short y_t[16384];      // [pos 64][c 256] bf16, swizzled

  const int tid = threadIdx.x;
  const int lane = tid & 63;
  const int wid = tid >> 6;
  const int g = lane >> 4;
  const int qh = lane & 15;
  const int bid = blockIdx.x;
  // XCD-chunked swizzle: XCD j owns winl [j*128, +128) -> the 4 windows
  // sharing each 128B output line are processed on ONE XCD, close in time.
  const int winl = ((bid & 7) << 7) | (bid >> 3);
  const int batch = batch0 + blockIdx.z;
  const size_t qofs = batched ? (size_t)blockIdx.z * QKV_STRIDE : 0;
  const float scale = 0.17677669529663687f;  // 1/sqrt(32)

  char* pbase = (char*)&P_lds[wid][0];

#pragma unroll
  for (int hi = 0; hi < 2; ++hi) {
    const int head = wid + hi * 4;
    const unsigned short* qb = q_w + qofs + (size_t)(winl * 8 + head) * 2048;
    const unsigned short* kb = k_w + qofs + (size_t)(winl * 8 + head) * 2048;
    const unsigned short* vb = v_w + qofs + (size_t)(winl * 8 + head) * 2048;

    bfx8 kf[4], qf[4];
#pragma unroll
    for (int t = 0; t < 4; ++t) {
      kf[t] = *(const bfx8*)(kb + (t * 16 + qh) * 32 + g * 8);
      qf[t] = *(const bfx8*)(qb + (t * 16 + qh) * 32 + g * 8);
    }
    // S^T[kpos][q] = sum_d K[kpos][d] * Q[q][d]
    f32x4 zero = {0.f, 0.f, 0.f, 0.f};
    f32x4 st[4][4];
#pragma unroll
    for (int kt = 0; kt < 4; ++kt)
#pragma unroll
      for (int qt = 0; qt < 4; ++qt)
        st[kt][qt] = __builtin_amdgcn_mfma_f32_16x16x32_bf16(kf[kt], qf[qt], zero, 0, 0, 0);

    // softmax over kpos (rows of S^T)
    float rv[4];
#pragma unroll
    for (int qt = 0; qt < 4; ++qt) {
      float m = -1e30f;
#pragma unroll
      for (int kt = 0; kt < 4; ++kt) {
        f32x4 v = st[kt][qt];
        m = fmaxf(m, fmaxf(fmaxf(v.x, v.y), fmaxf(v.z, v.w)));
      }
      m = fmaxf(m, __shfl_xor(m, 16, 64));
      m = fmaxf(m, __shfl_xor(m, 32, 64));
      float ssum = 0.f;
#pragma unroll
      for (int kt = 0; kt < 4; ++kt) {
        f32x4 v = st[kt][qt], e;
        e.x = __expf((v.x - m) * scale);
        e.y = __expf((v.y - m) * scale);
        e.z = __expf((v.z - m) * scale);
        e.w = __expf((v.w - m) * scale);
        ssum += e.x + e.y + e.z + e.w;
        st[kt][qt] = e;
      }
      ssum += __shfl_xor(ssum, 16, 64);
      ssum += __shfl_xor(ssum, 32, 64);
      rv[qt] = 1.f / ssum;
    }

    // PV: out^T[d][q] = sum_k V^T[d][k] * P
    f32x4 ot[2][4];
#pragma unroll
    for (int dt = 0; dt < 2; ++dt)
#pragma unroll
      for (int qt = 0; qt < 4; ++qt) ot[dt][qt] = zero;

#pragma unroll
    for (int s = 0; s < 2; ++s) {
#pragma unroll
      for (int qt = 0; qt < 4; ++qt) {
        int q = qt * 16 + qh;
        unsigned sw = ((unsigned)(q & 3)) << 4;
        float r = rv[qt];
#pragma unroll
        for (int k2 = 0; k2 < 2; ++k2) {
          f32x4 e = st[s * 2 + k2][qt];
          uint2 pv;
          pv.x = (unsigned)f2bf(e.x * r) | ((unsigned)f2bf(e.y * r) << 16);
          pv.y = (unsigned)f2bf(e.z * r) | ((unsigned)f2bf(e.w * r) << 16);
          unsigned byte = ((unsigned)q * 64 + (unsigned)(k2 * 32 + g * 8)) ^ sw;
          *(uint2*)(pbase + byte) = pv;
        }
      }
      bfx8 pf[4];
#pragma unroll
      for (int qt = 0; qt < 4; ++qt) {
        int q = qt * 16 + qh;
        unsigned byte = ((unsigned)q * 64 + (unsigned)(g * 16)) ^ (((unsigned)(q & 3)) << 4);
        pf[qt] = *(const bfx8*)(pbase + byte);
      }
#pragma unroll
      for (int dt = 0; dt < 2; ++dt) {
        bfx8 vf = *(const bfx8*)(vb + (dt * 16 + qh) * 64 + s * 32 + g * 8);
#pragma unroll
        for (int qt = 0; qt < 4; ++qt)
          ot[dt][qt] = __builtin_amdgcn_mfma_f32_16x16x32_bf16(vf, pf[qt], ot[dt][qt], 0, 0, 0);
      }
    }

    // attention output -> y_t[pos][c] (swizzled), c = head*32 + d
#pragma unroll
    for (int dt = 0; dt < 2; ++dt) {
      int cb = head * 32 + dt * 16 + g * 4;
#pragma unroll
      for (int qt = 0; qt < 4; ++qt) {
        int pos = qt * 16 + qh;
        f32x4 a = ot[dt][qt];
        uint2 pv;
        pv.x = (unsigned)f2bf(a.x) | ((unsigned)f2bf(a.y) << 16);
        pv.y = (unsigned)f2bf(a.z) | ((unsigned)f2bf(a.w) << 16);
        unsigned byte = ((unsigned)pos * 512 + (unsigned)cb * 2) ^ (((unsigned)(pos & 7)) << 4);
        *(uint2*)((char*)y_t + byte) = pv;
      }
    }
  }
  __syncthreads();

  // output conv: out[o][pos] = sum_c wp[o][c] * y[c][pos]; wave wid: o in [64*wid, +64)
  f32x4 acc[4][4];
#pragma unroll
  for (int i = 0; i < 4; ++i)
#pragma unroll
    for (int j = 0; j < 4; ++j) acc[i][j] = (f32x4){0.f, 0.f, 0.f, 0.f};

  for (int ks = 0; ks < 8; ++ks) {
    bfx8 af[4];
#pragma unroll
    for (int mt = 0; mt < 4; ++mt)
      af[mt] = *(const bfx8*)(wpbf + (wid * 64 + mt * 16 + qh) * 256 + ks * 32 + g * 8);
#pragma unroll
    for (int nt = 0; nt < 4; ++nt) {
      int pos = nt * 16 + qh;
      unsigned byte = ((unsigned)pos * 512 + (unsigned)(ks * 64 + g * 16)) ^ (((unsigned)(pos & 7)) << 4);
      bfx8 bfr = *(const bfx8*)((char*)y_t + byte);
#pragma unroll
      for (int mt = 0; mt < 4; ++mt)
        acc[mt][nt] = __builtin_amdgcn_mfma_f32_16x16x32_bf16(af[mt], bfr, acc[mt][nt], 0, 0, 0);
    }
  }

  const int wrow = winl >> 5, wcol = winl & 31;
  float* ob_ = out + (size_t)batch * NC * HW;
#pragma unroll
  for (int mt = 0; mt < 4; ++mt) {
    int o0 = wid * 64 + mt * 16 + g * 4;
    float b0 = bp[o0], b1 = bp[o0 + 1], b2 = bp[o0 + 2], b3 = bp[o0 + 3];
#pragma unroll
    for (int nt = 0; nt < 4; ++nt) {
      int pos = nt * 16 + qh;
      int h_img = wrow * 8 + (pos >> 3);
      int w_img = wcol * 8 + (pos & 7);
      float* pp = ob_ + (size_t)o0 * HW + h_img * 256 + w_img;
      pp[0]      = acc[mt][nt].x + b0;
      pp[HW]     = acc[mt][nt].y + b1;
      pp[2 * HW] = acc[mt][nt].z + b2;
      pp[3 * HW] = acc[mt][nt].w + b3;
    }
  }
}

extern "C" void kernel_launch(void* const* d_in, const int* in_sizes, int n_in,
                              void* d_out, int out_size, void* d_ws, size_t ws_size,
                              hipStream_t stream) {
  const float* q_feat = (const float*)d_in[0];
  const float* kv_feat = (const float*)d_in[1];
  const float* wq = (const float*)d_in[2];
  const float* bq = (const float*)d_in[3];
  const float* wk = (const float*)d_in[4];
  const float* bk = (const float*)d_in[5];
  const float* wv = (const float*)d_in[6];
  const float* bv = (const float*)d_in[7];
  const float* wp = (const float*)d_in[8];
  const float* bp = (const float*)d_in[9];
  float* out = (float*)d_out;

  unsigned short* wbf = (unsigned short*)d_ws;  // 4 x 65536 bf16 = 512 KB
  const size_t need_batched = 524288ul + 12ul * QKV_STRIDE * 2ul;  // ~403 MB

  hipLaunchKernelGGL(prep_weights, dim3(256), dim3(256), 0, stream, wq, wk, wv, wp, wbf);

  if (ws_size >= need_batched) {
    // all-batch path: 2 big launches, no inter-batch serialization bubbles
    unsigned short* q_w = wbf + 262144;
    unsigned short* k_w = q_w + 4 * QKV_STRIDE;
    unsigned short* v_w = k_w + 4 * QKV_STRIDE;
    hipLaunchKernelGGL(qkv_gemm, dim3(2048, 1, 4), dim3(256), 0, stream,
                       q_feat, kv_feat, wbf, bq, bk, bv, q_w, k_w, v_w, 0, 1);
    hipLaunchKernelGGL(attn_conv, dim3(1024, 1, 4), dim3(256), 0, stream,
                       q_w, k_w, v_w, wbf + 196608, bp, out, 0, 1);
  } else {
    // per-batch fallback (~97 MB workspace)
    unsigned short* q_w = wbf + 262144;
    unsigned short* k_w = q_w + QKV_STRIDE;
    unsigned short* v_w = k_w + QKV_STRIDE;
    for (int b = 0; b < 4; ++b) {
      hipLaunchKernelGGL(qkv_gemm, dim3(2048, 1, 1), dim3(256), 0, stream,
                         q_feat, kv_feat, wbf, bq, bk, bv, q_w, k_w, v_w, b, 0);
      hipLaunchKernelGGL(attn_conv, dim3(1024, 1, 1), dim3(256), 0, stream,
                         q_w, k_w, v_w, wbf + 196608, bp, out, b, 0);
    }
  }
}